// Round 1
// baseline (123.402 us; speedup 1.0000x reference)
//
#include <hip/hip_runtime.h>

#define M_ 8
#define D1_ 32
#define D2_ 32
#define E_ 256
#define K_ 2
#define L_ 16384
#define NSPECIAL_ 32
#define SIDX_ 8
#define NPLAYERS_ 4
#define H_ 256
#define P_ (D1_ * D2_)            // 1024 positions per batch elem
#define POL_COLS (L_ + SIDX_)     // 16392

// ---------------------------------------------------------------------------
// Kernel 1: per-(m,pos) partial dot products.
//   A[m,p] = dot(emb[m,p,:], Wp[0:256])
//   B[m,p] = dot(emb[m,p,:], Wp[256:512])
//   base[m] = dot(cls[m,:], Wp[512:768]) + bp
// One wave (64 lanes) per (m,p); lane i handles elements 4i..4i+3 (float4).
// ---------------------------------------------------------------------------
__global__ __launch_bounds__(64) void k_tables(
    const float* __restrict__ emb, const float* __restrict__ cls,
    const float* __restrict__ Wp, const float* __restrict__ bp,
    float* __restrict__ A, float* __restrict__ B, float* __restrict__ base)
{
    const int b = blockIdx.x;
    const int lane = threadIdx.x;

    if (b < M_ * P_) {
        // emb[m,r,c,e] flat = (m*1024 + p)*256 + e with p = r*D2 + c
        const float4 v  = ((const float4*)(emb + (size_t)b * E_))[lane];
        const float4 w0 = ((const float4*)(Wp))[lane];
        const float4 w1 = ((const float4*)(Wp + E_))[lane];
        float a  = v.x * w0.x + v.y * w0.y + v.z * w0.z + v.w * w0.w;
        float bb = v.x * w1.x + v.y * w1.y + v.z * w1.z + v.w * w1.w;
        #pragma unroll
        for (int off = 32; off > 0; off >>= 1) {
            a  += __shfl_down(a,  off, 64);
            bb += __shfl_down(bb, off, 64);
        }
        if (lane == 0) { A[b] = a; B[b] = bb; }
    } else {
        const int m = b - M_ * P_;
        const float4 v = ((const float4*)(cls + (size_t)m * E_))[lane];
        const float4 w = ((const float4*)(Wp + 2 * E_))[lane];
        float a = v.x * w.x + v.y * w.y + v.z * w.z + v.w * w.w;
        #pragma unroll
        for (int off = 32; off > 0; off >>= 1) a += __shfl_down(a, off, 64);
        if (lane == 0) base[m] = a + bp[0];
    }
}

// ---------------------------------------------------------------------------
// Kernel 2: the tiny MLP heads. One block (256 threads) per batch elem m.
//   hidden_s = relu(cls @ Ws1 + bs1); special_all = hidden_s @ Ws2 + bs2
//   hidden_v = relu(cls @ Wv1 + bv1); value      = hidden_v @ Wv2 + bv2
//   out[m, 16384 + si] = special_all[sidx[si]];  value -> tail of d_out
// ---------------------------------------------------------------------------
__global__ __launch_bounds__(256) void k_heads(
    const float* __restrict__ cls, const int* __restrict__ sidx,
    const float* __restrict__ Wv1, const float* __restrict__ bv1,
    const float* __restrict__ Wv2, const float* __restrict__ bv2,
    const float* __restrict__ Ws1, const float* __restrict__ bs1,
    const float* __restrict__ Ws2, const float* __restrict__ bs2,
    float* __restrict__ out)
{
    __shared__ float cl[E_];
    __shared__ float hs[H_];
    __shared__ float hv[H_];
    __shared__ float sp[NSPECIAL_];

    const int m = blockIdx.x;
    const int t = threadIdx.x;

    cl[t] = cls[(size_t)m * E_ + t];
    __syncthreads();

    // thread t = hidden unit t; weight reads coalesced across threads
    float as = bs1[t], av = bv1[t];
    #pragma unroll 4
    for (int e = 0; e < E_; ++e) {
        const float c = cl[e];
        as = fmaf(c, Ws1[(size_t)e * H_ + t], as);
        av = fmaf(c, Wv1[(size_t)e * H_ + t], av);
    }
    hs[t] = fmaxf(as, 0.f);
    hv[t] = fmaxf(av, 0.f);
    __syncthreads();

    if (t < NSPECIAL_) {
        float acc = bs2[t];
        #pragma unroll 4
        for (int h = 0; h < H_; ++h) acc = fmaf(hs[h], Ws2[(size_t)h * NSPECIAL_ + t], acc);
        sp[t] = acc;
    } else if (t >= 64 && t < 64 + NPLAYERS_) {
        const int n = t - 64;
        float acc = bv2[n];
        #pragma unroll 4
        for (int h = 0; h < H_; ++h) acc = fmaf(hv[h], Wv2[(size_t)h * NPLAYERS_ + n], acc);
        out[(size_t)M_ * POL_COLS + (size_t)m * NPLAYERS_ + n] = acc;  // value tail
    }
    __syncthreads();

    if (t < SIDX_) {
        out[(size_t)m * POL_COLS + L_ + t] = sp[sidx[t]];
    }
}

// ---------------------------------------------------------------------------
// Kernel 3: main policy fill.
//   out[m,l] = A[m,p0(l)] + B[m,p1(l)] + base[m]
// 64 blocks per m; thread = one l. int4 load of the 2 (row,col) pairs.
// Per-m A/B tables are 4 KB each -> L1-resident for the block's lookups.
// ---------------------------------------------------------------------------
__global__ __launch_bounds__(256) void k_policy(
    const int* __restrict__ sm,
    const float* __restrict__ A, const float* __restrict__ B,
    const float* __restrict__ base, float* __restrict__ out)
{
    const int b = blockIdx.x;
    const int m = b >> 6;                              // 64 blocks per m
    const int l = ((b & 63) << 8) + threadIdx.x;       // 0..16383
    const int4 s = ((const int4*)sm)[l];
    const int p0 = s.x * D2_ + s.y;
    const int p1 = s.z * D2_ + s.w;
    out[(size_t)m * POL_COLS + l] = A[m * P_ + p0] + B[m * P_ + p1] + base[m];
}

extern "C" void kernel_launch(void* const* d_in, const int* in_sizes, int n_in,
                              void* d_out, int out_size, void* d_ws, size_t ws_size,
                              hipStream_t stream) {
    const float* emb  = (const float*)d_in[0];
    const float* cls  = (const float*)d_in[1];
    const int*   sm   = (const int*)d_in[2];
    const int*   sidx = (const int*)d_in[3];
    const float* Wp   = (const float*)d_in[4];
    const float* bp   = (const float*)d_in[5];
    const float* Wv1  = (const float*)d_in[6];
    const float* bv1  = (const float*)d_in[7];
    const float* Wv2  = (const float*)d_in[8];
    const float* bv2  = (const float*)d_in[9];
    const float* Ws1  = (const float*)d_in[10];
    const float* bs1  = (const float*)d_in[11];
    const float* Ws2  = (const float*)d_in[12];
    const float* bs2  = (const float*)d_in[13];
    float* out = (float*)d_out;

    float* A    = (float*)d_ws;          // 8192 floats
    float* B    = A + M_ * P_;           // 8192 floats
    float* base = B + M_ * P_;           // 8 floats

    k_tables<<<M_ * P_ + M_, 64, 0, stream>>>(emb, cls, Wp, bp, A, B, base);
    k_heads<<<M_, 256, 0, stream>>>(cls, sidx, Wv1, bv1, Wv2, bv2,
                                    Ws1, bs1, Ws2, bs2, out);
    k_policy<<<M_ * (L_ / 256), 256, 0, stream>>>(sm, A, B, base, out);
}

// Round 3
// 85.892 us; speedup vs baseline: 1.4367x; 1.4367x over previous
//
#include <hip/hip_runtime.h>

#define M_ 8
#define D1_ 32
#define D2_ 32
#define E_ 256
#define K_ 2
#define L_ 16384
#define NSPECIAL_ 32
#define SIDX_ 8
#define NPLAYERS_ 4
#define H_ 256
#define P_ (D1_ * D2_)            // 1024 positions per batch elem
#define POL_COLS (L_ + SIDX_)     // 16392

#define NCHUNK 16                 // e-chunks for hidden-layer partials
#define CHUNK_E (E_ / NCHUNK)     // 16 e's per chunk

// ws layout (floats)
#define WS_A 0
#define WS_B (M_ * P_)                    // 8192
#define WS_BASE (2 * M_ * P_)             // 16384
#define WS_PART (2 * M_ * P_ + 256)       // 16640, partials: 2*8*16*256 = 65536 f
#define WS_NEED_BYTES ((WS_PART + 2 * M_ * NCHUNK * H_) * 4)

// ---------------------------------------------------------------------------
// K1 fused: [0,2048) A/B tables (4 waves/block, wave-per-position)
//           [2048,2050) cls base (wave-per-m)
//           [2050,2306) hidden partials: 2 heads x 8 m x 16 chunks
// ---------------------------------------------------------------------------
__global__ __launch_bounds__(256) void k_fused1(
    const float* __restrict__ emb, const float* __restrict__ cls,
    const float* __restrict__ Wp, const float* __restrict__ bp,
    const float* __restrict__ Ws1, const float* __restrict__ Wv1,
    float* __restrict__ ws)
{
    const int blk = blockIdx.x;
    const int tid = threadIdx.x;

    if (blk < 2048) {
        // ---- A/B tables: position b = blk*4 + wave over m*P ----
        const int wave = tid >> 6, lane = tid & 63;
        const int b = blk * 4 + wave;
        const float4 v  = ((const float4*)(emb + (size_t)b * E_))[lane];
        const float4 w0 = ((const float4*)(Wp))[lane];
        const float4 w1 = ((const float4*)(Wp + E_))[lane];
        float a  = v.x * w0.x + v.y * w0.y + v.z * w0.z + v.w * w0.w;
        float bb = v.x * w1.x + v.y * w1.y + v.z * w1.z + v.w * w1.w;
        #pragma unroll
        for (int off = 32; off > 0; off >>= 1) {
            a  += __shfl_down(a,  off, 64);
            bb += __shfl_down(bb, off, 64);
        }
        if (lane == 0) { ws[WS_A + b] = a; ws[WS_B + b] = bb; }
    } else if (blk < 2050) {
        // ---- base[m] = dot(cls[m], Wp[512:768]) + bp ----
        const int wave = tid >> 6, lane = tid & 63;
        const int m = (blk - 2048) * 4 + wave;
        const float4 v = ((const float4*)(cls + (size_t)m * E_))[lane];
        const float4 w = ((const float4*)(Wp + 2 * E_))[lane];
        float a = v.x * w.x + v.y * w.y + v.z * w.z + v.w * w.w;
        #pragma unroll
        for (int off = 32; off > 0; off >>= 1) a += __shfl_down(a, off, 64);
        if (lane == 0) ws[WS_BASE + m] = a + bp[0];
    } else {
        // ---- hidden partials: partial[head][m][chunk][t] ----
        const int idx  = blk - 2050;        // 0..255
        const int head = idx >> 7;          // 0 = special, 1 = value
        const int rem  = idx & 127;
        const int m    = rem >> 4;
        const int c    = rem & 15;
        const float* __restrict__ W1 = head ? Wv1 : Ws1;
        const int e0 = c * CHUNK_E;
        const float* __restrict__ cm = cls + (size_t)m * E_ + e0;
        float acc = 0.f;
        #pragma unroll
        for (int i = 0; i < CHUNK_E; ++i)
            acc = fmaf(cm[i], W1[(size_t)(e0 + i) * H_ + tid], acc);
        ws[WS_PART + (size_t)((head * M_ + m) * NCHUNK + c) * H_ + tid] = acc;
    }
}

// ---------------------------------------------------------------------------
// K2 fused: [0,512)   policy fill with LDS-staged A/B tables
//           [512,528) head second layer: reduce partials + relu + GEMV
// ---------------------------------------------------------------------------
__global__ __launch_bounds__(256) void k_fused2(
    const int* __restrict__ sm, const float* __restrict__ ws,
    const int* __restrict__ sidx,
    const float* __restrict__ bs1, const float* __restrict__ bv1,
    const float* __restrict__ Ws2, const float* __restrict__ bs2,
    const float* __restrict__ Wv2, const float* __restrict__ bv2,
    float* __restrict__ out)
{
    __shared__ float sh[2 * P_ + 64];
    const int blk = blockIdx.x;
    const int t = threadIdx.x;

    if (blk < 512) {
        // ---- policy: out[m,l] = A[m,p0] + B[m,p1] + base[m] ----
        float* As = sh;
        float* Bs = sh + P_;
        const int m = blk >> 6;
        ((float4*)As)[t] = ((const float4*)(ws + WS_A + (size_t)m * P_))[t];
        ((float4*)Bs)[t] = ((const float4*)(ws + WS_B + (size_t)m * P_))[t];
        const float bm = ws[WS_BASE + m];
        __syncthreads();
        const int l = ((blk & 63) << 8) + t;
        const int4 s = ((const int4*)sm)[l];
        out[(size_t)m * POL_COLS + l] = As[s.x * D2_ + s.y] + Bs[s.z * D2_ + s.w] + bm;
    } else {
        // ---- heads ----
        float* hid = sh;               // 256
        float* red = sh + H_;          // 256
        float* sp  = sh + 2 * H_;      // 32
        const int idx  = blk - 512;
        const int head = idx >> 3;     // 0 = special, 1 = value
        const int m    = idx & 7;

        float acc = head ? bv1[t] : bs1[t];
        const float* __restrict__ pb =
            ws + WS_PART + (size_t)((head * M_ + m) * NCHUNK) * H_ + t;
        #pragma unroll
        for (int c = 0; c < NCHUNK; ++c) acc += pb[c * H_];
        hid[t] = fmaxf(acc, 0.f);
        __syncthreads();

        if (head == 0) {
            // special: 32 outputs; thread t = (chunk c = t>>5 of 32 h, ns = t&31)
            const int ns = t & 31, c = t >> 5;
            float p = 0.f;
            #pragma unroll
            for (int i = 0; i < 32; ++i) {
                const int h = c * 32 + i;
                p = fmaf(hid[h], Ws2[(size_t)h * NSPECIAL_ + ns], p);
            }
            red[t] = p;
            __syncthreads();
            if (t < NSPECIAL_) {
                float s = bs2[t];
                #pragma unroll
                for (int c2 = 0; c2 < 8; ++c2) s += red[c2 * 32 + t];
                sp[t] = s;
            }
            __syncthreads();
            if (t < SIDX_)
                out[(size_t)m * POL_COLS + L_ + t] = sp[sidx[t]];
        } else {
            // value: 4 outputs; 128 threads: np = t&3, chunk c = t>>2 of 8 h
            if (t < 128) {
                const int np = t & 3, c = t >> 2;
                float p = 0.f;
                #pragma unroll
                for (int i = 0; i < 8; ++i) {
                    const int h = c * 8 + i;
                    p = fmaf(hid[h], Wv2[(size_t)h * NPLAYERS_ + np], p);
                }
                red[t] = p;
            }
            __syncthreads();
            if (t < NPLAYERS_) {
                float s = bv2[t];
                #pragma unroll
                for (int c2 = 0; c2 < 32; ++c2) s += red[c2 * 4 + t];
                out[(size_t)M_ * POL_COLS + (size_t)m * NPLAYERS_ + t] = s;
            }
        }
    }
}

// ---------------------------------------------------------------------------
// Fallback path (round-1 structure) if ws_size is too small for partials.
// ---------------------------------------------------------------------------
__global__ __launch_bounds__(256) void k_heads_fallback(
    const float* __restrict__ cls, const int* __restrict__ sidx,
    const float* __restrict__ Wv1, const float* __restrict__ bv1,
    const float* __restrict__ Wv2, const float* __restrict__ bv2,
    const float* __restrict__ Ws1, const float* __restrict__ bs1,
    const float* __restrict__ Ws2, const float* __restrict__ bs2,
    float* __restrict__ out)
{
    __shared__ float cl[E_];
    __shared__ float hs[H_];
    __shared__ float hv[H_];
    __shared__ float sp[NSPECIAL_];
    const int m = blockIdx.x;
    const int t = threadIdx.x;
    cl[t] = cls[(size_t)m * E_ + t];
    __syncthreads();
    float as = bs1[t], av = bv1[t];
    #pragma unroll 4
    for (int e = 0; e < E_; ++e) {
        const float c = cl[e];
        as = fmaf(c, Ws1[(size_t)e * H_ + t], as);
        av = fmaf(c, Wv1[(size_t)e * H_ + t], av);
    }
    hs[t] = fmaxf(as, 0.f);
    hv[t] = fmaxf(av, 0.f);
    __syncthreads();
    if (t < NSPECIAL_) {
        float acc = bs2[t];
        for (int h = 0; h < H_; ++h) acc = fmaf(hs[h], Ws2[(size_t)h * NSPECIAL_ + t], acc);
        sp[t] = acc;
    } else if (t >= 64 && t < 64 + NPLAYERS_) {
        const int n = t - 64;
        float acc = bv2[n];
        for (int h = 0; h < H_; ++h) acc = fmaf(hv[h], Wv2[(size_t)h * NPLAYERS_ + n], acc);
        out[(size_t)M_ * POL_COLS + (size_t)m * NPLAYERS_ + n] = acc;
    }
    __syncthreads();
    if (t < SIDX_) out[(size_t)m * POL_COLS + L_ + t] = sp[sidx[t]];
}

__global__ __launch_bounds__(64) void k_tables_fallback(
    const float* __restrict__ emb, const float* __restrict__ cls,
    const float* __restrict__ Wp, const float* __restrict__ bp,
    float* __restrict__ ws)
{
    const int b = blockIdx.x;
    const int lane = threadIdx.x;
    if (b < M_ * P_) {
        const float4 v  = ((const float4*)(emb + (size_t)b * E_))[lane];
        const float4 w0 = ((const float4*)(Wp))[lane];
        const float4 w1 = ((const float4*)(Wp + E_))[lane];
        float a  = v.x * w0.x + v.y * w0.y + v.z * w0.z + v.w * w0.w;
        float bb = v.x * w1.x + v.y * w1.y + v.z * w1.z + v.w * w1.w;
        #pragma unroll
        for (int off = 32; off > 0; off >>= 1) {
            a  += __shfl_down(a,  off, 64);
            bb += __shfl_down(bb, off, 64);
        }
        if (lane == 0) { ws[WS_A + b] = a; ws[WS_B + b] = bb; }
    } else {
        const int m = b - M_ * P_;
        const float4 v = ((const float4*)(cls + (size_t)m * E_))[lane];
        const float4 w = ((const float4*)(Wp + 2 * E_))[lane];
        float a = v.x * w.x + v.y * w.y + v.z * w.z + v.w * w.w;
        #pragma unroll
        for (int off = 32; off > 0; off >>= 1) a += __shfl_down(a, off, 64);
        if (lane == 0) ws[WS_BASE + m] = a + bp[0];
    }
}

__global__ __launch_bounds__(256) void k_policy_fallback(
    const int* __restrict__ sm, const float* __restrict__ ws,
    float* __restrict__ out)
{
    __shared__ float As[P_], Bs[P_];
    const int b = blockIdx.x;
    const int m = b >> 6;
    ((float4*)As)[threadIdx.x] = ((const float4*)(ws + WS_A + (size_t)m * P_))[threadIdx.x];
    ((float4*)Bs)[threadIdx.x] = ((const float4*)(ws + WS_B + (size_t)m * P_))[threadIdx.x];
    const float bm = ws[WS_BASE + m];
    __syncthreads();
    const int l = ((b & 63) << 8) + threadIdx.x;
    const int4 s = ((const int4*)sm)[l];
    out[(size_t)m * POL_COLS + l] = As[s.x * D2_ + s.y] + Bs[s.z * D2_ + s.w] + bm;
}

extern "C" void kernel_launch(void* const* d_in, const int* in_sizes, int n_in,
                              void* d_out, int out_size, void* d_ws, size_t ws_size,
                              hipStream_t stream) {
    const float* emb  = (const float*)d_in[0];
    const float* cls  = (const float*)d_in[1];
    const int*   sm   = (const int*)d_in[2];
    const int*   sidx = (const int*)d_in[3];
    const float* Wp   = (const float*)d_in[4];
    const float* bp   = (const float*)d_in[5];
    const float* Wv1  = (const float*)d_in[6];
    const float* bv1  = (const float*)d_in[7];
    const float* Wv2  = (const float*)d_in[8];
    const float* bv2  = (const float*)d_in[9];
    const float* Ws1  = (const float*)d_in[10];
    const float* bs1  = (const float*)d_in[11];
    const float* Ws2  = (const float*)d_in[12];
    const float* bs2  = (const float*)d_in[13];
    float* out = (float*)d_out;
    float* ws  = (float*)d_ws;

    if (ws_size >= (size_t)WS_NEED_BYTES) {
        k_fused1<<<2050 + 2 * M_ * NCHUNK, 256, 0, stream>>>(
            emb, cls, Wp, bp, Ws1, Wv1, ws);
        k_fused2<<<512 + 16, 256, 0, stream>>>(
            sm, ws, sidx, bs1, bv1, Ws2, bs2, Wv2, bv2, out);
    } else {
        k_tables_fallback<<<M_ * P_ + M_, 64, 0, stream>>>(emb, cls, Wp, bp, ws);
        k_heads_fallback<<<M_, 256, 0, stream>>>(cls, sidx, Wv1, bv1, Wv2, bv2,
                                                 Ws1, bs1, Ws2, bs2, out);
        k_policy_fallback<<<M_ * (L_ / 256), 256, 0, stream>>>(sm, ws, out);
    }
}